// Round 7
// baseline (2108.731 us; speedup 1.0000x reference)
//
#include <hip/hip_runtime.h>
#include <hip/hip_cooperative_groups.h>
#include <math.h>

namespace cg = cooperative_groups;

#define BB 4
#define UU 512
#define DD 80
#define HH 8
#define FFND 2048
#define LL 12
#define SEGC 32
#define LCC 50
#define RCC 8
#define NSEG 16
#define RCL 128
#define KK 640
#define ROWS (BB*KK)        // 2560
#define OUTD 768
#define EPSF 1e-5f
#define SCALEF 0.31622776601683794f  // (D/H)^-0.5
#define NTH 256

typedef __attribute__((ext_vector_type(8))) short bf16x8;
typedef __attribute__((ext_vector_type(4))) float f32x4;
typedef unsigned short u16;

__device__ inline u16 f2bf(float f) {
  unsigned int u = __float_as_uint(f);
  u += 0x7fffu + ((u >> 16) & 1u);
  return (u16)(u >> 16);
}
__device__ inline ushort4 f4bf(float4 v) {
  ushort4 r;
  r.x = f2bf(v.x); r.y = f2bf(v.y); r.z = f2bf(v.z); r.w = f2bf(v.w);
  return r;
}
__device__ inline bf16x8 bz8() {
  bf16x8 r = {0, 0, 0, 0, 0, 0, 0, 0};
  return r;
}
__device__ inline bf16x8 fragf32(const float* __restrict__ rowp, int k) {
  if (k < 80) {
    float4 a = *reinterpret_cast<const float4*>(rowp + k);
    float4 b = *reinterpret_cast<const float4*>(rowp + k + 4);
    bf16x8 r;
    r[0] = (short)f2bf(a.x); r[1] = (short)f2bf(a.y);
    r[2] = (short)f2bf(a.z); r[3] = (short)f2bf(a.w);
    r[4] = (short)f2bf(b.x); r[5] = (short)f2bf(b.y);
    r[6] = (short)f2bf(b.z); r[7] = (short)f2bf(b.w);
    return r;
  }
  return bz8();
}
__device__ inline bf16x8 fragbf(const u16* __restrict__ rowp, int k) {
  if (k < 80) return *reinterpret_cast<const bf16x8*>(rowp + k);
  return bz8();
}

struct KParams {
  const float *mel, *lng, *lnb, *Wq, *bq, *Wkv, *bkv, *Wo, *bo;
  const float *ffg, *ffb, *W1, *b1, *W2, *b2, *og, *ob, *Wp, *bp;
  const int* lens;
  float *out, *x, *qkv, *attn;
  u16 *w1bf, *w2bf, *wqbf, *wkvbf, *wobf, *wpbf;
};

// LDS strips: per-wave h strip 16 rows x 264 shorts (stride 264 keeps 16B
// alignment for b128 frags; FFN2 partials alias the same strips as float).
#define HSTRIDE 264
#define HSTRIP (16 * HSTRIDE)     // shorts per wave strip (8448 B)
#define PSTRIP (HSTRIP / 2)       // floats per wave strip alias

__global__ __launch_bounds__(NTH, 2) void k_fused(KParams p) {
  cg::grid_group grid = cg::this_grid();
  __shared__ __align__(16) short s_h[4 * HSTRIP];   // 33792 B (attn aliases)
  __shared__ float s_v[16 * 84];                    // 5376 B
  __shared__ __align__(16) short s_f[16 * 104];     // 3328 B
  __shared__ float s_mu[16], s_ri[16];

  const int tid = threadIdx.x;
  const int w = tid >> 6, lane = tid & 63;
  const int m = lane & 15, q = lane >> 4;
  const int nB = gridDim.x;
  const int nW = nB * 4;
  const int gw = blockIdx.x * 4 + w;
  const int gtid = blockIdx.x * NTH + tid;
  const int nT = nB * NTH;

  // ================= P0: gather + weight convert =================
  for (int idx = gtid; idx < ROWS * DD; idx += nT) {
    int d = idx % DD;
    int row = idx / DD;
    int b = row / KK;
    int j = row % KK;
    int pos;
    if (j < RCL) {
      int i = j >> 3, r = j & 7;
      pos = (i < NSEG - 1) ? (i + 1) * SEGC + r : UU + r;
    } else {
      pos = j - RCL;
    }
    p.x[idx] = p.mel[(b * (UU + RCC) + pos) * DD + d];
  }
  for (int t = gtid; t < 1075200; t += nT) {
    const float* src; u16* dst; int i;
    if (t < 491520)       { src = p.W1;  dst = p.w1bf;  i = t; }
    else if (t < 983040)  { src = p.W2;  dst = p.w2bf;  i = t - 491520; }
    else if (t < 1002240) { src = p.Wq;  dst = p.wqbf;  i = t - 983040; }
    else if (t < 1040640) { src = p.Wkv; dst = p.wkvbf; i = t - 1002240; }
    else if (t < 1059840) { src = p.Wo;  dst = p.wobf;  i = t - 1040640; }
    else                  { src = p.Wp;  dst = p.wpbf;  i = t - 1059840; }
    float4 v = reinterpret_cast<const float4*>(src)[i];
    reinterpret_cast<ushort4*>(dst)[i] = f4bf(v);
  }
  grid.sync();

  for (int l = 0; l < LL; ++l) {
    const u16* lwq  = p.wqbf  + l * DD * DD;
    const u16* lwkv = p.wkvbf + l * 2 * DD * DD;
    const u16* lwo  = p.wobf  + l * DD * DD;
    const u16* lw1  = p.w1bf  + l * FFND * DD;
    const u16* lw2  = p.w2bf  + l * FFND * DD;
    const float* lgl = p.lng + l * DD;
    const float* lbl = p.lnb + l * DD;
    const float* bql = p.bq + l * DD;
    const float* bkvl = p.bkv + l * 2 * DD;
    const float* bol = p.bo + l * DD;
    const float* b1l = p.b1 + l * FFND;
    const float* b2l = p.b2 + l * DD;
    const float* fgl = p.ffg + l * DD;
    const float* fbl = p.ffb + l * DD;
    const float* ogl = p.og + l * DD;
    const float* obl = p.ob + l * DD;

    // ================= P1: LN_in + QKV (2400 wave-tasks) =================
    for (int t = gw; t < 2400; t += nW) {
      int rt = t / 15, ct = t - rt * 15;
      int r0 = rt * 16;
      int c = ct * 16 + m;
      const float* xr = &p.x[(r0 + m) * DD];
      float xv[3][8];
      float sm = 0.f, sq = 0.f;
#pragma unroll
      for (int kk = 0; kk < 3; ++kk) {
        int base = kk * 32 + q * 8;
        if (base < 80) {
          float4 a = *reinterpret_cast<const float4*>(xr + base);
          float4 b = *reinterpret_cast<const float4*>(xr + base + 4);
          xv[kk][0] = a.x; xv[kk][1] = a.y; xv[kk][2] = a.z; xv[kk][3] = a.w;
          xv[kk][4] = b.x; xv[kk][5] = b.y; xv[kk][6] = b.z; xv[kk][7] = b.w;
#pragma unroll
          for (int j = 0; j < 8; ++j) { sm += xv[kk][j]; sq += xv[kk][j] * xv[kk][j]; }
        }
      }
      sm += __shfl_xor(sm, 16); sq += __shfl_xor(sq, 16);
      sm += __shfl_xor(sm, 32); sq += __shfl_xor(sq, 32);
      float mu = sm * (1.f / DD);
      float ri = rsqrtf(sq * (1.f / DD) - mu * mu + EPSF);
      bf16x8 a[3];
#pragma unroll
      for (int kk = 0; kk < 3; ++kk) {
        int base = kk * 32 + q * 8;
        if (base < 80) {
          float4 g1 = *reinterpret_cast<const float4*>(lgl + base);
          float4 g2 = *reinterpret_cast<const float4*>(lgl + base + 4);
          float4 h1 = *reinterpret_cast<const float4*>(lbl + base);
          float4 h2 = *reinterpret_cast<const float4*>(lbl + base + 4);
          float gg[8] = {g1.x, g1.y, g1.z, g1.w, g2.x, g2.y, g2.z, g2.w};
          float hh[8] = {h1.x, h1.y, h1.z, h1.w, h2.x, h2.y, h2.z, h2.w};
#pragma unroll
          for (int j = 0; j < 8; ++j)
            a[kk][j] = (short)f2bf((xv[kk][j] - mu) * ri * gg[j] + hh[j]);
        } else {
          a[kk] = bz8();
        }
      }
      const u16* wr = (c < 80) ? &lwq[c * DD] : &lwkv[(c - 80) * DD];
      f32x4 acc = {};
#pragma unroll
      for (int kk = 0; kk < 3; ++kk) {
        bf16x8 b = fragbf(wr, kk * 32 + q * 8);
        acc = __builtin_amdgcn_mfma_f32_16x16x32_bf16(a[kk], b, acc, 0, 0, 0);
      }
      float bv = (c < 80) ? bql[c] : bkvl[c - 80];
#pragma unroll
      for (int r = 0; r < 4; ++r)
        p.qkv[(r0 + q * 4 + r) * 240 + c] = acc[r] + bv;
    }
    grid.sync();

    // ================= P2: attention (512 block-tasks) =================
    for (int task = blockIdx.x; task < 512; task += nB) {
      float* s_k  = (float*)s_h;       // 10*97
      float* s_vv = (float*)s_h + 970; // 10*97
      float* s_q  = (float*)s_h + 1940; // 10*44
      float* s_p  = (float*)s_h + 2384; // 40*91
      float* s_kb = (float*)s_h + 6024; // 90
      float* s_dn = (float*)s_h + 6114; // 40
      int i = task & 15, h = (task >> 4) & 7, b = task >> 7;
      int s0 = i * SEGC - LCC; if (s0 < 0) s0 = 0;
      int nk = RCC + (i + 1) * SEGC - s0;  // 40..90
      int len = p.lens[b];
      if (tid < nk) {
        int kr = (tid < RCC) ? i * RCC + tid : RCL + s0 + (tid - RCC);
        const float* kp = &p.qkv[(b * KK + kr) * 240 + 80 + h * 10];
#pragma unroll
        for (int d = 0; d < 10; ++d) {
          s_k[d * 97 + tid] = kp[d];
          s_vv[d * 97 + tid] = kp[80 + d];
        }
        s_kb[tid] = (kr >= len + RCL) ? -1e8f : 0.f;
      }
      if (tid < 40) {
        int qr = (tid < RCC) ? i * RCC + tid : RCL + i * SEGC + (tid - RCC);
        const float* qp = &p.qkv[(b * KK + qr) * 240 + h * 10];
#pragma unroll
        for (int d = 0; d < 10; ++d) s_q[d * 44 + tid] = qp[d];
      }
      __syncthreads();
      for (int qi = w; qi < 40; qi += 4) {
        for (int jk = lane; jk < nk; jk += 64) {
          float dot = 0.f;
#pragma unroll
          for (int d = 0; d < 10; ++d) dot += s_q[d * 44 + qi] * s_k[d * 97 + jk];
          s_p[qi * 91 + jk] = dot * SCALEF + s_kb[jk];
        }
      }
      __syncthreads();
      if (tid < 40) {
        float mx = -1e30f;
        for (int kx = 0; kx < nk; ++kx) mx = fmaxf(mx, s_p[tid * 91 + kx]);
        float sum = 0.f;
        for (int kx = 0; kx < nk; ++kx) {
          float ev = __expf(s_p[tid * 91 + kx] - mx);
          s_p[tid * 91 + kx] = ev;
          sum += ev;
        }
        s_dn[tid] = 1.f / sum;
      }
      __syncthreads();
      for (int po = tid; po < 400; po += NTH) {
        int qi = po / 10, d = po % 10;
        float o0 = 0.f, o1 = 0.f, o2 = 0.f, o3 = 0.f;
        int kx = 0, nk4 = nk & ~3;
        for (; kx < nk4; kx += 4) {
          o0 += s_p[qi * 91 + kx]     * s_vv[d * 97 + kx];
          o1 += s_p[qi * 91 + kx + 1] * s_vv[d * 97 + kx + 1];
          o2 += s_p[qi * 91 + kx + 2] * s_vv[d * 97 + kx + 2];
          o3 += s_p[qi * 91 + kx + 3] * s_vv[d * 97 + kx + 3];
        }
        for (; kx < nk; ++kx) o0 += s_p[qi * 91 + kx] * s_vv[d * 97 + kx];
        float o = (o0 + o1) + (o2 + o3);
        int qr = (qi < RCC) ? i * RCC + qi : RCL + i * SEGC + (qi - RCC);
        p.attn[(b * KK + qr) * DD + h * 10 + d] = o * s_dn[qi];
      }
      __syncthreads();
    }
    grid.sync();

    // ===== P3: tail — oproj + LN_ff + FFN1 + FFN2 + LN_out (160 tasks) =====
    for (int task = blockIdx.x; task < 160; task += nB) {
      int r0 = task * 16;
      // ---- oproj: 16x80 = attn_bf @ Wo^T; wave w -> col tile w (+w0 tile4)
      bf16x8 af[3];
#pragma unroll
      for (int kk = 0; kk < 3; ++kk)
        af[kk] = fragf32(&p.attn[(r0 + m) * DD], kk * 32 + q * 8);
      f32x4 o0 = {};
      const u16* wrow = lwo + (w * 16 + m) * DD;
#pragma unroll
      for (int kk = 0; kk < 3; ++kk)
        o0 = __builtin_amdgcn_mfma_f32_16x16x32_bf16(
            af[kk], fragbf(wrow, kk * 32 + q * 8), o0, 0, 0, 0);
      f32x4 o1 = {};
      if (w == 0) {
        const u16* wrow4 = lwo + (64 + m) * DD;
#pragma unroll
        for (int kk = 0; kk < 3; ++kk)
          o1 = __builtin_amdgcn_mfma_f32_16x16x32_bf16(
              af[kk], fragbf(wrow4, kk * 32 + q * 8), o1, 0, 0, 0);
      }
      {
        int c = w * 16 + m;
        float bv = bol[c];
#pragma unroll
        for (int r = 0; r < 4; ++r) {
          int lrow = q * 4 + r;
          s_v[lrow * 84 + c] = o0[r] + bv + p.x[(r0 + lrow) * DD + c];
        }
        if (w == 0) {
          int c4 = 64 + m;
          float bv4 = bol[c4];
#pragma unroll
          for (int r = 0; r < 4; ++r) {
            int lrow = q * 4 + r;
            s_v[lrow * 84 + c4] = o1[r] + bv4 + p.x[(r0 + lrow) * DD + c4];
          }
        }
      }
      __syncthreads();
      // ---- LN_ff stats ----
      if (tid < 64) {
        int row = tid & 15, prt = tid >> 4;
        float sm = 0.f, sq = 0.f;
        for (int j = 0; j < 20; ++j) {
          float v = s_v[row * 84 + prt * 20 + j];
          sm += v; sq += v * v;
        }
        sm += __shfl_xor(sm, 16); sq += __shfl_xor(sq, 16);
        sm += __shfl_xor(sm, 32); sq += __shfl_xor(sq, 32);
        if (prt == 0) {
          float mu = sm * (1.f / DD);
          s_mu[row] = mu;
          s_ri[row] = rsqrtf(sq * (1.f / DD) - mu * mu + EPSF);
        }
      }
      __syncthreads();
      {
        int row = tid >> 4, cg5 = tid & 15;
        float mu = s_mu[row], ri = s_ri[row];
#pragma unroll
        for (int j = 0; j < 5; ++j) {
          int c = cg5 * 5 + j;
          s_f[row * 104 + c] = (short)f2bf((s_v[row * 84 + c] - mu) * ri * fgl[c] + fbl[c]);
        }
        if (cg5 == 15)
          for (int c = 80; c < 104; ++c) s_f[row * 104 + c] = 0;
      }
      __syncthreads();
      // ---- FFN1 + FFN2, wave w owns hidden cols {hc*1024 + w*256 ..+256} ----
      bf16x8 ff[3];
#pragma unroll
      for (int kk = 0; kk < 3; ++kk)
        ff[kk] = *reinterpret_cast<const bf16x8*>(&s_f[m * 104 + kk * 32 + q * 8]);
      short* hw = &s_h[w * HSTRIP];
      f32x4 acc2[5] = {};
#pragma unroll 1
      for (int hc = 0; hc < 2; ++hc) {
        int cb = hc * 1024 + w * 256;
        // FFN1: 16 col-tiles -> own strip (no cross-wave use, no barrier)
#pragma unroll
        for (int t8 = 0; t8 < 16; ++t8) {
          int col = cb + t8 * 16 + m;
          const u16* wr1 = lw1 + col * DD;
          f32x4 a1 = {};
#pragma unroll
          for (int kk = 0; kk < 3; ++kk)
            a1 = __builtin_amdgcn_mfma_f32_16x16x32_bf16(
                ff[kk], fragbf(wr1, kk * 32 + q * 8), a1, 0, 0, 0);
          float bb = b1l[col];
#pragma unroll
          for (int r = 0; r < 4; ++r)
            hw[(q * 4 + r) * HSTRIDE + t8 * 16 + m] = (short)f2bf(fmaxf(a1[r] + bb, 0.f));
        }
        // FFN2 partial over this 256-K chunk (A from own strip)
#pragma unroll
        for (int kk2 = 0; kk2 < 8; ++kk2) {
          bf16x8 ah = *reinterpret_cast<const bf16x8*>(&hw[m * HSTRIDE + kk2 * 32 + q * 8]);
#pragma unroll
          for (int t5 = 0; t5 < 5; ++t5) {
            bf16x8 b = *reinterpret_cast<const bf16x8*>(
                &lw2[(t5 * 16 + m) * FFND + cb + kk2 * 32 + q * 8]);
            acc2[t5] = __builtin_amdgcn_mfma_f32_16x16x32_bf16(ah, b, acc2[t5], 0, 0, 0);
          }
        }
      }
      // stash partials into own strip (float alias), reduce across waves
      {
        float* sp = (float*)s_h + w * PSTRIP;
#pragma unroll
        for (int t5 = 0; t5 < 5; ++t5)
#pragma unroll
          for (int r = 0; r < 4; ++r)
            sp[(q * 4 + r) * 84 + t5 * 16 + m] = acc2[t5][r];
      }
      __syncthreads();
      {
        int row = tid >> 4, cg5 = tid & 15;
        float* sp = (float*)s_h;
#pragma unroll
        for (int j = 0; j < 5; ++j) {
          int c = cg5 * 5 + j;
          int o = row * 84 + c;
          float v = sp[o] + sp[PSTRIP + o] + sp[2 * PSTRIP + o] + sp[3 * PSTRIP + o] +
                    b2l[c] + s_v[o];
          s_v[o] = v;
        }
      }
      __syncthreads();
      // ---- LN_out ----
      if (tid < 64) {
        int row = tid & 15, prt = tid >> 4;
        float sm = 0.f, sq = 0.f;
        for (int j = 0; j < 20; ++j) {
          float v = s_v[row * 84 + prt * 20 + j];
          sm += v; sq += v * v;
        }
        sm += __shfl_xor(sm, 16); sq += __shfl_xor(sq, 16);
        sm += __shfl_xor(sm, 32); sq += __shfl_xor(sq, 32);
        if (prt == 0) {
          float mu = sm * (1.f / DD);
          s_mu[row] = mu;
          s_ri[row] = rsqrtf(sq * (1.f / DD) - mu * mu + EPSF);
        }
      }
      __syncthreads();
      {
        int row = tid >> 4, cg5 = tid & 15;
        float mu = s_mu[row], ri = s_ri[row];
#pragma unroll
        for (int j = 0; j < 5; ++j) {
          int c = cg5 * 5 + j;
          p.x[(r0 + row) * DD + c] = (s_v[row * 84 + c] - mu) * ri * ogl[c] + obl[c];
        }
      }
      __syncthreads();
    }
    grid.sync();
  }

  // ================= P7: final projection (6144 wave-tasks) =================
  for (int t = gw; t < 6144; t += nW) {
    int rt2 = t % 128, ct2 = t / 128;
    int r0 = rt2 * 16;
    int gr = r0 + m;
    int xrow = (gr >> 9) * KK + RCL + (gr & 511);
    bf16x8 af[3];
#pragma unroll
    for (int kk = 0; kk < 3; ++kk)
      af[kk] = fragf32(&p.x[xrow * DD], kk * 32 + q * 8);
    const u16* wr = p.wpbf + (ct2 * 16 + m) * DD;
    f32x4 acc = {};
#pragma unroll
    for (int kk = 0; kk < 3; ++kk)
      acc = __builtin_amdgcn_mfma_f32_16x16x32_bf16(
          af[kk], fragbf(wr, kk * 32 + q * 8), acc, 0, 0, 0);
    int c = ct2 * 16 + m;
    float bv = p.bp[c];
#pragma unroll
    for (int r = 0; r < 4; ++r)
      p.out[(r0 + q * 4 + r) * OUTD + c] = acc[r] + bv;
  }
  if (blockIdx.x == 0 && tid < BB)
    p.out[BB * UU * OUTD + tid] = (float)p.lens[tid];
}

extern "C" void kernel_launch(void* const* d_in, const int* in_sizes, int n_in,
                              void* d_out, int out_size, void* d_ws, size_t ws_size,
                              hipStream_t stream) {
  KParams prm;
  prm.mel = (const float*)d_in[0];
  prm.lng = (const float*)d_in[1];
  prm.lnb = (const float*)d_in[2];
  prm.Wq  = (const float*)d_in[3];
  prm.bq  = (const float*)d_in[4];
  prm.Wkv = (const float*)d_in[5];
  prm.bkv = (const float*)d_in[6];
  prm.Wo  = (const float*)d_in[7];
  prm.bo  = (const float*)d_in[8];
  prm.ffg = (const float*)d_in[9];
  prm.ffb = (const float*)d_in[10];
  prm.W1  = (const float*)d_in[11];
  prm.b1  = (const float*)d_in[12];
  prm.W2  = (const float*)d_in[13];
  prm.b2  = (const float*)d_in[14];
  prm.og  = (const float*)d_in[15];
  prm.ob  = (const float*)d_in[16];
  prm.Wp  = (const float*)d_in[17];
  prm.bp  = (const float*)d_in[18];
  prm.lens = (const int*)d_in[19];
  prm.out = (float*)d_out;

  float* ws = (float*)d_ws;
  prm.x    = ws;                       // 204800 f
  prm.qkv  = prm.x + ROWS * DD;        // 614400 f
  prm.attn = prm.qkv + ROWS * 240;     // 204800 f
  prm.w1bf = (u16*)(prm.attn + ROWS * DD);            // 1966080 sh
  prm.w2bf = prm.w1bf + LL * FFND * DD;               // 1966080 sh
  prm.wqbf = prm.w2bf + LL * FFND * DD;               // 76800 sh
  prm.wkvbf = prm.wqbf + LL * DD * DD;                // 153600 sh
  prm.wobf = prm.wkvbf + LL * 2 * DD * DD;            // 76800 sh
  prm.wpbf = prm.wobf + LL * DD * DD;                 // 61440 sh

  int maxB = 0;
  if (hipOccupancyMaxActiveBlocksPerMultiprocessor(&maxB, k_fused, NTH, 0) !=
          hipSuccess || maxB < 1)
    maxB = 1;
  int nblk = (maxB >= 2) ? 512 : 256;
  void* args[] = {&prm};
  hipError_t e = hipLaunchCooperativeKernel((const void*)k_fused, dim3(nblk),
                                            dim3(NTH), args, 0, stream);
  if (e != hipSuccess && nblk > 256) {
    (void)hipGetLastError();
    hipLaunchCooperativeKernel((const void*)k_fused, dim3(256), dim3(NTH),
                               args, 0, stream);
  }
}